// Round 1
// baseline (967.220 us; speedup 1.0000x reference)
//
#include <hip/hip_runtime.h>
#include <math.h>

// Problem constants (B,C,H,W = 8,256,64,64; N = H*W = 4096)
#define BQ 8
#define CQ 256
#define NQ 4096

static __device__ __forceinline__ float4 ld4(const float* p) { return *(const float4*)p; }

static constexpr float LOG2E = 1.4426950408889634f;

// -------- K1: f' = (wq . x)*log2e, g = wk . x   (per b, per n) --------
__global__ void k_fg(const float* __restrict__ x, const float* __restrict__ wq,
                     const float* __restrict__ wk, float* __restrict__ fs,
                     float* __restrict__ g) {
    int b = blockIdx.y;
    int n = blockIdx.x * 256 + threadIdx.x;
    const float* xb = x + (size_t)b * CQ * NQ + n;
    float accf = 0.f, accg = 0.f;
#pragma unroll 8
    for (int c = 0; c < CQ; ++c) {
        float v = xb[(size_t)c * NQ];
        accf = fmaf(wq[c], v, accf);
        accg = fmaf(wk[c], v, accg);
    }
    fs[b * NQ + n] = accf * LOG2E;
    g[b * NQ + n]  = accg;
}

// -------- K1b: per-batch max/min of f' (for safe softmax shift) --------
__global__ void k_minmax(const float* __restrict__ fs, float* __restrict__ fmx,
                         float* __restrict__ fmn) {
    int b = blockIdx.x;
    const float* f = fs + b * NQ;
    float mx = -1e30f, mn = 1e30f;
    for (int i = threadIdx.x; i < NQ; i += 256) {
        float v = f[i];
        mx = fmaxf(mx, v);
        mn = fminf(mn, v);
    }
    for (int off = 32; off; off >>= 1) {
        mx = fmaxf(mx, __shfl_down(mx, off));
        mn = fminf(mn, __shfl_down(mn, off));
    }
    __shared__ float smx[4], smn[4];
    int wid = threadIdx.x >> 6;
    if ((threadIdx.x & 63) == 0) { smx[wid] = mx; smn[wid] = mn; }
    __syncthreads();
    if (threadIdx.x == 0) {
        mx = fmaxf(fmaxf(smx[0], smx[1]), fmaxf(smx[2], smx[3]));
        mn = fminf(fminf(smn[0], smn[1]), fminf(smn[2], smn[3]));
        fmx[b] = mx;
        fmn[b] = mn;
    }
}

// -------- K2: hT[b][n][c] = sum_k wv[c][k] * x[b][k][n]  (tiled GEMM) --------
// block: 256 thr, tile 64n x 64c, k-chunks of 64; thread tile 4n x 4c
__global__ void k_h(const float* __restrict__ x, const float* __restrict__ wv,
                    float* __restrict__ hT) {
    __shared__ float xs[64][64];   // [k][n]
    __shared__ float wvs[64][64];  // [k][c]
    int b = blockIdx.z;
    int n0 = blockIdx.x * 64;
    int c0 = blockIdx.y * 64;
    int tid = threadIdx.x;
    int tx = tid & 15;      // n-group
    int ty = tid >> 4;      // c-group
    float acc[4][4] = {};
    const float* xb = x + (size_t)b * CQ * NQ;

    for (int k0 = 0; k0 < CQ; k0 += 64) {
        // stage x[k0..k0+64][n0..n0+64]
#pragma unroll
        for (int i = 0; i < 4; ++i) {
            int idx = tid * 4 + i * 1024;
            int kk = idx >> 6, nn = idx & 63;
            *(float4*)&xs[kk][nn] = ld4(&xb[(size_t)(k0 + kk) * NQ + n0 + nn]);
        }
        // stage wv[c0..c0+64][k0..k0+64], transposed to [k][c]
#pragma unroll
        for (int i = 0; i < 4; ++i) {
            int idx = tid * 4 + i * 1024;
            int cc = idx >> 6, kk = idx & 63;
            float4 v = ld4(&wv[(size_t)(c0 + cc) * CQ + k0 + kk]);
            wvs[kk + 0][cc] = v.x;
            wvs[kk + 1][cc] = v.y;
            wvs[kk + 2][cc] = v.z;
            wvs[kk + 3][cc] = v.w;
        }
        __syncthreads();
#pragma unroll 4
        for (int k = 0; k < 64; ++k) {
            float4 xv = ld4(&xs[k][tx * 4]);
            float4 wvv = ld4(&wvs[k][ty * 4]);
            float xa[4] = {xv.x, xv.y, xv.z, xv.w};
            float wa[4] = {wvv.x, wvv.y, wvv.z, wvv.w};
#pragma unroll
            for (int i = 0; i < 4; ++i)
#pragma unroll
                for (int j = 0; j < 4; ++j) acc[i][j] = fmaf(xa[i], wa[j], acc[i][j]);
        }
        __syncthreads();
    }
#pragma unroll
    for (int ni = 0; ni < 4; ++ni) {
        float4 o = make_float4(acc[ni][0], acc[ni][1], acc[ni][2], acc[ni][3]);
        *(float4*)&hT[((size_t)b * NQ + n0 + tx * 4 + ni) * CQ + c0 + ty * 4] = o;
    }
}

// -------- K3: o[b,c,m] = (1-gam) * (sum_n hT[n][c] e[n,m]) / Z_m + gam * x[b,c,m]
// e[n,m] = exp2(f'_n * g_m - M_m) generated on the fly.
// block: 256 thr, tile 128c x 128m, n-chunks of 32; thread tile 8c x 8m.
__global__ void k_attn(const float* __restrict__ hT, const float* __restrict__ fs,
                       const float* __restrict__ g, const float* __restrict__ fmxs,
                       const float* __restrict__ fmns, const float* __restrict__ x,
                       const float* __restrict__ gamma, float* __restrict__ out) {
    __shared__ float hs[32][128];   // [n][c] 16KB
    __shared__ float es[32][128];   // [n][m] 16KB
    __shared__ float fsh[32];
    __shared__ float zred[2][128];

    int b = blockIdx.z;
    int m0 = blockIdx.x * 128;
    int c0 = blockIdx.y * 128;
    int tid = threadIdx.x;
    int tx = tid & 15;   // m-group: m = m0 + tx*8 + j
    int ty = tid >> 4;   // c-group: c = c0 + ty*8 + i

    // e-generation layout: fixed column me per thread, rows rbase+2k
    int me = tid & 127;
    int rbase = tid >> 7;

    float gm  = g[b * NQ + m0 + me];
    float fmx = fmxs[b], fmn = fmns[b];
    float Mm  = (gm >= 0.f) ? gm * fmx : gm * fmn;
    float zacc = 0.f;

    float acc[8][8] = {};
    const float* hTb = hT + (size_t)b * NQ * CQ;
    const float* fb  = fs + b * NQ;

    for (int n0 = 0; n0 < NQ; n0 += 32) {
        if (tid < 32) fsh[tid] = fb[n0 + tid];
        // stage hT[n0..n0+32][c0..c0+128]
#pragma unroll
        for (int i = 0; i < 4; ++i) {
            int idx = tid * 4 + i * 1024;
            int nn = idx >> 7, cc = idx & 127;
            *(float4*)&hs[nn][cc] = ld4(&hTb[(size_t)(n0 + nn) * CQ + c0 + cc]);
        }
        __syncthreads();
        // generate e tile (each element exactly once; zacc accumulates per fixed column)
#pragma unroll
        for (int k = 0; k < 16; ++k) {
            int r = rbase + 2 * k;
            float e = exp2f(fmaf(fsh[r], gm, -Mm));
            es[r][me] = e;
            zacc += e;
        }
        __syncthreads();
        // 8c x 8m register tile GEMM over this n-chunk
#pragma unroll 4
        for (int n = 0; n < 32; ++n) {
            float4 h0 = ld4(&hs[n][ty * 8]);
            float4 h1 = ld4(&hs[n][ty * 8 + 4]);
            float4 e0 = ld4(&es[n][tx * 8]);
            float4 e1 = ld4(&es[n][tx * 8 + 4]);
            float hv[8] = {h0.x, h0.y, h0.z, h0.w, h1.x, h1.y, h1.z, h1.w};
            float ev[8] = {e0.x, e0.y, e0.z, e0.w, e1.x, e1.y, e1.z, e1.w};
#pragma unroll
            for (int i = 0; i < 8; ++i)
#pragma unroll
                for (int j = 0; j < 8; ++j) acc[i][j] = fmaf(hv[i], ev[j], acc[i][j]);
        }
        __syncthreads();
    }

    zred[rbase][me] = zacc;
    __syncthreads();

    float gam = gamma[0];
    float om_gam = 1.f - gam;
#pragma unroll
    for (int i = 0; i < 8; ++i) {
        int c = c0 + ty * 8 + i;
        size_t base = ((size_t)b * CQ + c) * NQ + m0 + tx * 8;
        float4 xv0 = ld4(&x[base]);
        float4 xv1 = ld4(&x[base + 4]);
        float xv[8] = {xv0.x, xv0.y, xv0.z, xv0.w, xv1.x, xv1.y, xv1.z, xv1.w};
        float o[8];
#pragma unroll
        for (int j = 0; j < 8; ++j) {
            int mm = tx * 8 + j;
            float Z = zred[0][mm] + zred[1][mm];
            o[j] = om_gam * acc[i][j] / Z + gam * xv[j];
        }
        *(float4*)&out[base]     = make_float4(o[0], o[1], o[2], o[3]);
        *(float4*)&out[base + 4] = make_float4(o[4], o[5], o[6], o[7]);
    }
}

extern "C" void kernel_launch(void* const* d_in, const int* in_sizes, int n_in,
                              void* d_out, int out_size, void* d_ws, size_t ws_size,
                              hipStream_t stream) {
    const float* x     = (const float*)d_in[0];
    const float* wq    = (const float*)d_in[1];
    const float* wk    = (const float*)d_in[2];
    const float* wv    = (const float*)d_in[3];
    const float* gamma = (const float*)d_in[4];
    float* out = (float*)d_out;

    // ws layout (floats): fs[B*N] | g[B*N] | fmx[B] | fmn[B] | pad | hT[B*N*C]
    float* ws  = (float*)d_ws;
    float* fs  = ws;
    float* g   = ws + BQ * NQ;
    float* fmx = ws + 2 * BQ * NQ;
    float* fmn = fmx + BQ;
    float* hT  = ws + 2 * BQ * NQ + 64;  // 16B-aligned; needs ~33.8MB total ws

    hipLaunchKernelGGL(k_fg, dim3(NQ / 256, BQ), dim3(256), 0, stream, x, wq, wk, fs, g);
    hipLaunchKernelGGL(k_minmax, dim3(BQ), dim3(256), 0, stream, fs, fmx, fmn);
    hipLaunchKernelGGL(k_h, dim3(NQ / 64, CQ / 64, BQ), dim3(256), 0, stream, x, wv, hT);
    hipLaunchKernelGGL(k_attn, dim3(NQ / 128, CQ / 128, BQ), dim3(256), 0, stream,
                       hT, fs, g, fmx, fmn, x, gamma, out);
}

// Round 2
// 345.230 us; speedup vs baseline: 2.8017x; 2.8017x over previous
//
#include <hip/hip_runtime.h>
#include <math.h>

// Problem constants (B,C,H,W = 8,256,64,64; N = H*W = 4096)
#define BQ 8
#define CQ 256
#define NQ 4096

typedef short s16x8 __attribute__((ext_vector_type(8)));
typedef short s16x4 __attribute__((ext_vector_type(4)));
typedef float f32x4 __attribute__((ext_vector_type(4)));

static __device__ __forceinline__ float4 ld4(const float* p) { return *(const float4*)p; }

static constexpr float LOG2E = 1.4426950408889634f;

// float -> bf16 bits (RNE via native cast)
static __device__ __forceinline__ short f2bf(float f) {
    return __builtin_bit_cast(short, (__bf16)f);
}

// -------- K1: f' = (wq . x)*log2e, g = wk . x   (per b, per n) --------
__global__ void k_fg(const float* __restrict__ x, const float* __restrict__ wq,
                     const float* __restrict__ wk, float* __restrict__ fs,
                     float* __restrict__ g) {
    int b = blockIdx.y;
    int n = blockIdx.x * 256 + threadIdx.x;
    const float* xb = x + (size_t)b * CQ * NQ + n;
    float accf = 0.f, accg = 0.f;
#pragma unroll 8
    for (int c = 0; c < CQ; ++c) {
        float v = xb[(size_t)c * NQ];
        accf = fmaf(wq[c], v, accf);
        accg = fmaf(wk[c], v, accg);
    }
    fs[b * NQ + n] = accf * LOG2E;
    g[b * NQ + n]  = accg;
}

// -------- K1b: per-batch max/min of f' --------
__global__ void k_minmax(const float* __restrict__ fs, float* __restrict__ fmx,
                         float* __restrict__ fmn) {
    int b = blockIdx.x;
    const float* f = fs + b * NQ;
    float mx = -1e30f, mn = 1e30f;
    for (int i = threadIdx.x; i < NQ; i += 256) {
        float v = f[i];
        mx = fmaxf(mx, v);
        mn = fminf(mn, v);
    }
    for (int off = 32; off; off >>= 1) {
        mx = fmaxf(mx, __shfl_down(mx, off));
        mn = fminf(mn, __shfl_down(mn, off));
    }
    __shared__ float smx[4], smn[4];
    int wid = threadIdx.x >> 6;
    if ((threadIdx.x & 63) == 0) { smx[wid] = mx; smn[wid] = mn; }
    __syncthreads();
    if (threadIdx.x == 0) {
        mx = fmaxf(fmaxf(smx[0], smx[1]), fmaxf(smx[2], smx[3]));
        mn = fminf(fminf(smn[0], smn[1]), fminf(smn[2], smn[3]));
        fmx[b] = mx;
        fmn[b] = mn;
    }
}

// -------- K2: h[b][c][n] (bf16) = sum_k wv[c][k] * x[b][k][n]  (tiled GEMM) --------
// block: 256 thr, tile 64n x 64c, k-chunks of 64; thread tile 4n x 4c
__global__ void k_h(const float* __restrict__ x, const float* __restrict__ wv,
                    short* __restrict__ hbf) {
    __shared__ float xs[64][64];   // [k][n]
    __shared__ float wvs[64][64];  // [k][c]
    int b = blockIdx.z;
    int n0 = blockIdx.x * 64;
    int c0 = blockIdx.y * 64;
    int tid = threadIdx.x;
    int tx = tid & 15;      // n-group
    int ty = tid >> 4;      // c-group
    float acc[4][4] = {};
    const float* xb = x + (size_t)b * CQ * NQ;

    for (int k0 = 0; k0 < CQ; k0 += 64) {
#pragma unroll
        for (int i = 0; i < 4; ++i) {
            int idx = tid * 4 + i * 1024;
            int kk = idx >> 6, nn = idx & 63;
            *(float4*)&xs[kk][nn] = ld4(&xb[(size_t)(k0 + kk) * NQ + n0 + nn]);
        }
#pragma unroll
        for (int i = 0; i < 4; ++i) {
            int idx = tid * 4 + i * 1024;
            int cc = idx >> 6, kk = idx & 63;
            float4 v = ld4(&wv[(size_t)(c0 + cc) * CQ + k0 + kk]);
            wvs[kk + 0][cc] = v.x;
            wvs[kk + 1][cc] = v.y;
            wvs[kk + 2][cc] = v.z;
            wvs[kk + 3][cc] = v.w;
        }
        __syncthreads();
#pragma unroll 4
        for (int k = 0; k < 64; ++k) {
            float4 xv = ld4(&xs[k][tx * 4]);
            float4 wvv = ld4(&wvs[k][ty * 4]);
            float xa[4] = {xv.x, xv.y, xv.z, xv.w};
            float wa[4] = {wvv.x, wvv.y, wvv.z, wvv.w};
#pragma unroll
            for (int i = 0; i < 4; ++i)
#pragma unroll
                for (int j = 0; j < 4; ++j) acc[i][j] = fmaf(xa[i], wa[j], acc[i][j]);
        }
        __syncthreads();
    }
#pragma unroll
    for (int cj = 0; cj < 4; ++cj) {
        s16x4 v;
#pragma unroll
        for (int ni = 0; ni < 4; ++ni) v[ni] = f2bf(acc[ni][cj]);
        *(s16x4*)&hbf[(size_t)b * CQ * NQ + (size_t)(c0 + ty * 4 + cj) * NQ + n0 + tx * 4] = v;
    }
}

// -------- K3 (MFMA): o[b,c,m] = (1-gam)*(sum_n h[c][n]*e[n,m])/Z_m + gam*x[b,c,m]
// e[n,m] = exp2(f'_n * g_m - M_m) generated in registers in B-fragment layout.
// Block: 256 thr (4 waves, 2wc x 2wm). Block tile 256c x 64m; wave tile 128c x 32m.
// Per wave: 8 jc x 2 jm frags of mfma_f32_16x16x32_bf16; K-loop over n, 32/step.
// No LDS, no barriers. Grid: 512 blocks, b = bid&7 (one batch per XCD for L2 reuse).
__global__ void __launch_bounds__(256) k_attn(
    const short* __restrict__ hbf, const float* __restrict__ fsp,
    const float* __restrict__ gp, const float* __restrict__ fmxs,
    const float* __restrict__ fmns, const float* __restrict__ x,
    const float* __restrict__ gamma, float* __restrict__ out) {
    int bid = blockIdx.x;
    int b = bid & 7;            // batch -> XCD affinity (2.1MB h slice fits 4MB L2)
    int mblk = bid >> 3;        // 0..63
    int tid = threadIdx.x;
    int l = tid & 63;
    int w = tid >> 6;
    int wm = w & 1, wc = w >> 1;
    int q = l >> 4;             // k-slot (A/B frag k = q*8 + i)
    int cr = l & 15;            // A row (c) / B col (m) within frag

    float fmx = fmxs[b], fmn = fmns[b];
    const float* gb = gp + b * NQ;
    int mbase = mblk * 64 + wm * 32 + cr;
    float gj[2], nM[2], zac[2];
#pragma unroll
    for (int jm = 0; jm < 2; ++jm) {
        float gv = gb[mbase + jm * 16];
        gj[jm] = gv;
        nM[jm] = -((gv >= 0.f) ? gv * fmx : gv * fmn);   // -max_n f'_n*g_m
        zac[jm] = 0.f;
    }

    const float* fb = fsp + b * NQ;
    const short* hb = hbf + (size_t)b * CQ * NQ;
    int hrow[8];
#pragma unroll
    for (int jc = 0; jc < 8; ++jc) hrow[jc] = (wc * 128 + jc * 16 + cr) * NQ;

    f32x4 acc[8][2];
#pragma unroll
    for (int jc = 0; jc < 8; ++jc)
#pragma unroll
        for (int jm = 0; jm < 2; ++jm) acc[jc][jm] = (f32x4){0.f, 0.f, 0.f, 0.f};

    for (int n0 = 0; n0 < NQ; n0 += 32) {
        int kb = n0 + q * 8;
        float fq[8];
#pragma unroll
        for (int i = 0; i < 8; ++i) fq[i] = fb[kb + i];
        // B-frags: e in registers, Z accumulated on the fly
        s16x8 bv[2];
#pragma unroll
        for (int jm = 0; jm < 2; ++jm) {
            float z = zac[jm];
#pragma unroll
            for (int i = 0; i < 8; ++i) {
                float e = exp2f(fmaf(fq[i], gj[jm], nM[jm]));
                z += e;
                bv[jm][i] = f2bf(e);
            }
            zac[jm] = z;
        }
        // A-frags direct from global (16B/lane, 64B-coalesced per c-row, L2-hot)
#pragma unroll
        for (int jc = 0; jc < 8; ++jc) {
            s16x8 av = *(const s16x8*)(hb + hrow[jc] + kb);
            acc[jc][0] = __builtin_amdgcn_mfma_f32_16x16x32_bf16(av, bv[0], acc[jc][0], 0, 0, 0);
            acc[jc][1] = __builtin_amdgcn_mfma_f32_16x16x32_bf16(av, bv[1], acc[jc][1], 0, 0, 0);
        }
    }

    // Z: butterfly over the 4 k-slot lane groups (xor 16, 32)
#pragma unroll
    for (int jm = 0; jm < 2; ++jm) {
        float z = zac[jm];
        z += __shfl_xor(z, 16);
        z += __shfl_xor(z, 32);
        zac[jm] = z;
    }
    float gam = gamma[0];
    float omg = 1.f - gam;
    float rz[2] = {omg / zac[0], omg / zac[1]};

    // C/D layout: col(m) = lane&15, row(c) = (lane>>4)*4 + reg
#pragma unroll
    for (int jc = 0; jc < 8; ++jc) {
#pragma unroll
        for (int r = 0; r < 4; ++r) {
            int c = wc * 128 + jc * 16 + q * 4 + r;
            size_t base = ((size_t)b * CQ + c) * NQ + (size_t)mblk * 64 + wm * 32;
#pragma unroll
            for (int jm = 0; jm < 2; ++jm) {
                size_t idx = base + jm * 16 + cr;
                out[idx] = fmaf(gam, x[idx], acc[jc][jm][r] * rz[jm]);
            }
        }
    }
}

extern "C" void kernel_launch(void* const* d_in, const int* in_sizes, int n_in,
                              void* d_out, int out_size, void* d_ws, size_t ws_size,
                              hipStream_t stream) {
    const float* x     = (const float*)d_in[0];
    const float* wq    = (const float*)d_in[1];
    const float* wk    = (const float*)d_in[2];
    const float* wv    = (const float*)d_in[3];
    const float* gamma = (const float*)d_in[4];
    float* out = (float*)d_out;

    // ws layout (floats): fs[B*N] | g[B*N] | fmx[B] | fmn[B] | pad | h bf16 [B*C*N]
    float* ws  = (float*)d_ws;
    float* fs  = ws;
    float* g   = ws + BQ * NQ;
    float* fmx = ws + 2 * BQ * NQ;
    float* fmn = fmx + BQ;
    short* hbf = (short*)(ws + 2 * BQ * NQ + 64);  // 16B-aligned; ~17MB total ws use

    hipLaunchKernelGGL(k_fg, dim3(NQ / 256, BQ), dim3(256), 0, stream, x, wq, wk, fs, g);
    hipLaunchKernelGGL(k_minmax, dim3(BQ), dim3(256), 0, stream, fs, fmx, fmn);
    hipLaunchKernelGGL(k_h, dim3(NQ / 64, CQ / 64, BQ), dim3(256), 0, stream, x, wv, hbf);
    hipLaunchKernelGGL(k_attn, dim3(BQ * (NQ / 64)), dim3(256), 0, stream,
                       hbf, fs, g, fmx, fmn, x, gamma, out);
}

// Round 3
// 129.868 us; speedup vs baseline: 7.4477x; 2.6583x over previous
//
#include <hip/hip_runtime.h>
#include <math.h>

// Problem constants (B,C,H,W = 8,256,64,64; N = H*W = 4096)
#define BQ 8
#define CQ 256
#define NQ 4096
#define MT 128          // m-tile per block
#define NSTEP (NQ / 32) // 128 K-chunks of 32

typedef short s16x8 __attribute__((ext_vector_type(8)));
typedef short s16x4 __attribute__((ext_vector_type(4)));
typedef float f32x4 __attribute__((ext_vector_type(4)));

static __device__ __forceinline__ float4 ld4(const float* p) { return *(const float4*)p; }

static constexpr float LOG2E = 1.4426950408889634f;

static __device__ __forceinline__ short f2bf(float f) {
    return __builtin_bit_cast(short, (__bf16)f);
}

// -------- K1: f' = (wq.x)*log2e, g = wk.x, and xbf = bf16(x) --------
__global__ void k_fg(const float* __restrict__ x, const float* __restrict__ wq,
                     const float* __restrict__ wk, float* __restrict__ fs,
                     float* __restrict__ g, short* __restrict__ xbf) {
    int b = blockIdx.y;
    int n = blockIdx.x * 256 + threadIdx.x;
    const float* xb = x + (size_t)b * CQ * NQ + n;
    short* xo = xbf + (size_t)b * CQ * NQ + n;
    float accf = 0.f, accg = 0.f;
#pragma unroll 8
    for (int c = 0; c < CQ; ++c) {
        float v = xb[(size_t)c * NQ];
        accf = fmaf(wq[c], v, accf);
        accg = fmaf(wk[c], v, accg);
        xo[(size_t)c * NQ] = f2bf(v);
    }
    fs[b * NQ + n] = accf * LOG2E;
    g[b * NQ + n]  = accg;
}

// -------- K1b: per-batch max/min of f' --------
__global__ void k_minmax(const float* __restrict__ fs, float* __restrict__ fmx,
                         float* __restrict__ fmn) {
    int b = blockIdx.x;
    const float* f = fs + b * NQ;
    float mx = -1e30f, mn = 1e30f;
    for (int i = threadIdx.x; i < NQ; i += 256) {
        float v = f[i];
        mx = fmaxf(mx, v);
        mn = fminf(mn, v);
    }
    for (int off = 32; off; off >>= 1) {
        mx = fmaxf(mx, __shfl_down(mx, off));
        mn = fminf(mn, __shfl_down(mn, off));
    }
    __shared__ float smx[4], smn[4];
    int wid = threadIdx.x >> 6;
    if ((threadIdx.x & 63) == 0) { smx[wid] = mx; smn[wid] = mn; }
    __syncthreads();
    if (threadIdx.x == 0) {
        mx = fmaxf(fmaxf(smx[0], smx[1]), fmaxf(smx[2], smx[3]));
        mn = fminf(fminf(smn[0], smn[1]), fminf(smn[2], smn[3]));
        fmx[b] = mx;
        fmn[b] = mn;
    }
}

// -------- K2 fused: y[c][m] = sum_n x[c][n] e[n,m];  o = (1-g)*wv*(y/Z) + g*x --------
// 512 thr (8 waves: wc = w&1 c-half, wm = w>>1 m-quarter). Block tile 256c x 128m.
// Wave tile (GEMM1): 128c x 32m, e in-register B-frags, A staged via global_load_lds
// double-buffer (16KB tiles). Epilogue: y/Z -> bf16 -> swizzled LDS (64KB), then
// GEMM2 (wv * y_norm, K=256) fused with gamma/x epilogue.
__global__ void __launch_bounds__(512, 2) k_attn(
    const short* __restrict__ xbf, const float* __restrict__ fsp,
    const float* __restrict__ gp, const float* __restrict__ fmxs,
    const float* __restrict__ fmns, const float* __restrict__ wv,
    const float* __restrict__ x, const float* __restrict__ gamma,
    float* __restrict__ out) {
    __shared__ __align__(16) char smem[65536];  // stage dbuf aliases [0,32KB); y_lds = 64KB

    int bid = blockIdx.x;
    int b = bid & 7;            // batch -> XCD affinity (2MB xbf slice per XCD L2)
    int mblk = bid >> 3;        // 0..31
    int m0 = mblk * MT;
    int tid = threadIdx.x;
    int l = tid & 63;
    int w = tid >> 6;           // 0..7
    int wc = w & 1;             // c-half
    int wm = w >> 1;            // m-quarter
    int q = l >> 4;             // k-slot
    int cr = l & 15;            // A-row / B-col within frag

    float fmx = fmxs[b], fmn = fmns[b];
    const float* gb = gp + b * NQ;
    float gj[2], nM[2], zac[2];
#pragma unroll
    for (int jm = 0; jm < 2; ++jm) {
        float gv = gb[m0 + wm * 32 + jm * 16 + cr];
        gj[jm] = gv;
        nM[jm] = -((gv >= 0.f) ? gv * fmx : gv * fmn);
        zac[jm] = 0.f;
    }

    const float* fb = fsp + b * NQ;
    const short* xb = xbf + (size_t)b * CQ * NQ;

    f32x4 acc[8][2];
#pragma unroll
    for (int jc = 0; jc < 8; ++jc)
#pragma unroll
        for (int jm = 0; jm < 2; ++jm) acc[jc][jm] = (f32x4){0.f, 0.f, 0.f, 0.f};

    // ---- stage chunk 0 ----
#pragma unroll
    for (int r2 = 0; r2 < 2; ++r2) {
        int off = tid * 16 + r2 * 8192;
        int row = off >> 6, nb = off & 63;
        const short* src = xb + (size_t)row * NQ + (nb >> 1);
        __builtin_amdgcn_global_load_lds(
            (const __attribute__((address_space(1))) void*)src,
            (__attribute__((address_space(3))) void*)(smem + off), 16, 0, 0);
    }
    float4 fqa = *(const float4*)(fb + q * 8);
    float4 fqb = *(const float4*)(fb + q * 8 + 4);
    __syncthreads();

    for (int t = 0; t < NSTEP; ++t) {
        const char* cbuf = smem + (t & 1) * 16384;
        int n0n = ((t + 1) & (NSTEP - 1)) * 32;
        // stage next tile (async, drains at loop-end barrier)
        if (t + 1 < NSTEP) {
            char* nbuf = smem + ((t + 1) & 1) * 16384;
#pragma unroll
            for (int r2 = 0; r2 < 2; ++r2) {
                int off = tid * 16 + r2 * 8192;
                int row = off >> 6, nb = off & 63;
                const short* src = xb + (size_t)row * NQ + n0n + (nb >> 1);
                __builtin_amdgcn_global_load_lds(
                    (const __attribute__((address_space(1))) void*)src,
                    (__attribute__((address_space(3))) void*)(nbuf + off), 16, 0, 0);
            }
        }
        // prefetch next f chunk
        float4 fqa_n = *(const float4*)(fb + n0n + q * 8);
        float4 fqb_n = *(const float4*)(fb + n0n + q * 8 + 4);
        // e-gen: B-frags in registers + running Z
        float fq[8] = {fqa.x, fqa.y, fqa.z, fqa.w, fqb.x, fqb.y, fqb.z, fqb.w};
        s16x8 bv[2];
#pragma unroll
        for (int jm = 0; jm < 2; ++jm) {
            float z = zac[jm];
#pragma unroll
            for (int i = 0; i < 8; ++i) {
                float e = __builtin_amdgcn_exp2f(fmaf(fq[i], gj[jm], nM[jm]));
                z += e;
                bv[jm][i] = f2bf(e);
            }
            zac[jm] = z;
        }
        // A-frags from LDS tile [256c][32n] (uniform 8 lanes per 16B slot: conflict-optimal)
#pragma unroll
        for (int jc = 0; jc < 8; ++jc) {
            s16x8 av = *(const s16x8*)(cbuf + (wc * 128 + jc * 16 + cr) * 64 + q * 16);
            acc[jc][0] = __builtin_amdgcn_mfma_f32_16x16x32_bf16(av, bv[0], acc[jc][0], 0, 0, 0);
            acc[jc][1] = __builtin_amdgcn_mfma_f32_16x16x32_bf16(av, bv[1], acc[jc][1], 0, 0, 0);
        }
        fqa = fqa_n;
        fqb = fqb_n;
        __syncthreads();   // drains stage vmcnt + releases cur buffer
    }

    // ---- Z finalize: butterfly over the 4 k-slot groups ----
    float rzl[2];
#pragma unroll
    for (int jm = 0; jm < 2; ++jm) {
        float z = zac[jm];
        z += __shfl_xor(z, 16);
        z += __shfl_xor(z, 32);
        rzl[jm] = 1.0f / z;
    }

    // ---- y_norm -> LDS (bf16, XOR-swizzled rows of 512B, 16B granule) ----
#pragma unroll
    for (int jc = 0; jc < 8; ++jc) {
#pragma unroll
        for (int jm = 0; jm < 2; ++jm) {
            int mloc = wm * 32 + jm * 16 + cr;
            int bir = (wc * 256 + jc * 32 + q * 8) ^ ((mloc & 7) << 4);
            s16x4 v;
#pragma unroll
            for (int r = 0; r < 4; ++r) v[r] = f2bf(acc[jc][jm][r] * rzl[jm]);
            *(s16x4*)(smem + mloc * 512 + bir) = v;
        }
    }
    __syncthreads();

    // ---- GEMM2: o[c_out][m] = wv[c_out][:] . y_norm[:][m], K=256 ----
    int co0 = w * 32;
    f32x4 acc2[2][8];
#pragma unroll
    for (int j2 = 0; j2 < 2; ++j2)
#pragma unroll
        for (int jm2 = 0; jm2 < 8; ++jm2) acc2[j2][jm2] = (f32x4){0.f, 0.f, 0.f, 0.f};

#pragma unroll 2
    for (int ks = 0; ks < 8; ++ks) {
        s16x8 a2[2];
#pragma unroll
        for (int j2 = 0; j2 < 2; ++j2) {
            const float* wr = wv + (size_t)(co0 + j2 * 16 + cr) * CQ + ks * 32 + q * 8;
            float4 wa = ld4(wr);
            float4 wb = ld4(wr + 4);
            a2[j2][0] = f2bf(wa.x); a2[j2][1] = f2bf(wa.y);
            a2[j2][2] = f2bf(wa.z); a2[j2][3] = f2bf(wa.w);
            a2[j2][4] = f2bf(wb.x); a2[j2][5] = f2bf(wb.y);
            a2[j2][6] = f2bf(wb.z); a2[j2][7] = f2bf(wb.w);
        }
#pragma unroll
        for (int jm2 = 0; jm2 < 8; ++jm2) {
            int mloc = jm2 * 16 + cr;
            s16x8 b2 = *(const s16x8*)(smem + mloc * 512 + ((ks * 64 + q * 16) ^ ((mloc & 7) << 4)));
            acc2[0][jm2] = __builtin_amdgcn_mfma_f32_16x16x32_bf16(a2[0], b2, acc2[0][jm2], 0, 0, 0);
            acc2[1][jm2] = __builtin_amdgcn_mfma_f32_16x16x32_bf16(a2[1], b2, acc2[1][jm2], 0, 0, 0);
        }
    }

    // ---- epilogue: out = (1-gam)*acc2 (+ gam*x), nontemporal stores ----
    float gam = gamma[0];
    float omg = 1.f - gam;
    if (gam != 0.f) {
#pragma unroll
        for (int j2 = 0; j2 < 2; ++j2)
#pragma unroll
            for (int jm2 = 0; jm2 < 8; ++jm2)
#pragma unroll
                for (int r = 0; r < 4; ++r) {
                    int c_out = co0 + j2 * 16 + q * 4 + r;
                    size_t idx = ((size_t)b * CQ + c_out) * NQ + m0 + jm2 * 16 + cr;
                    __builtin_nontemporal_store(
                        fmaf(gam, x[idx], acc2[j2][jm2][r] * omg), out + idx);
                }
    } else {
#pragma unroll
        for (int j2 = 0; j2 < 2; ++j2)
#pragma unroll
            for (int jm2 = 0; jm2 < 8; ++jm2)
#pragma unroll
                for (int r = 0; r < 4; ++r) {
                    int c_out = co0 + j2 * 16 + q * 4 + r;
                    size_t idx = ((size_t)b * CQ + c_out) * NQ + m0 + jm2 * 16 + cr;
                    __builtin_nontemporal_store(acc2[j2][jm2][r] * omg, out + idx);
                }
    }
}

extern "C" void kernel_launch(void* const* d_in, const int* in_sizes, int n_in,
                              void* d_out, int out_size, void* d_ws, size_t ws_size,
                              hipStream_t stream) {
    const float* x     = (const float*)d_in[0];
    const float* wq    = (const float*)d_in[1];
    const float* wk    = (const float*)d_in[2];
    const float* wv    = (const float*)d_in[3];
    const float* gamma = (const float*)d_in[4];
    float* out = (float*)d_out;

    // ws (floats): fs[B*N] | g[B*N] | fmx[B] | fmn[B] | pad -> xbf (bf16) [B*C*N]  (~17.1MB)
    float* ws  = (float*)d_ws;
    float* fs  = ws;
    float* g   = ws + BQ * NQ;
    float* fmx = ws + 2 * BQ * NQ;
    float* fmn = fmx + BQ;
    short* xbf = (short*)(ws + 2 * BQ * NQ + 64);

    hipLaunchKernelGGL(k_fg, dim3(NQ / 256, BQ), dim3(256), 0, stream, x, wq, wk, fs, g, xbf);
    hipLaunchKernelGGL(k_minmax, dim3(BQ), dim3(256), 0, stream, fs, fmx, fmn);
    hipLaunchKernelGGL(k_attn, dim3(BQ * (NQ / MT)), dim3(512), 0, stream,
                       xbf, fs, g, fmx, fmn, wv, x, gamma, out);
}